// Round 10
// baseline (2134.797 us; speedup 1.0000x reference)
//
#include <hip/hip_runtime.h>
#include <math.h>

#define EPS_GN 1e-5f
#define ACC_DOUBLES 260

// ---------------------------------------------------------------------------
__device__ __forceinline__ void block_reduce_acc(double s, double s2, double* accn) {
  #pragma unroll
  for (int o = 32; o > 0; o >>= 1) {
    s  += __shfl_down(s, o, 64);
    s2 += __shfl_down(s2, o, 64);
  }
  __shared__ double red[8];
  int wv = threadIdx.x >> 6;
  if ((threadIdx.x & 63) == 0) { red[wv] = s; red[4 + wv] = s2; }
  __syncthreads();
  if (threadIdx.x == 0) {
    double ts = red[0] + red[1] + red[2] + red[3];
    double t2 = red[4] + red[5] + red[6] + red[7];
    atomicAdd(&accn[0], ts);
    atomicAdd(&accn[1], t2);
  }
}

__device__ __forceinline__ float quant_scale(const double* wsum, double invCnt) {
  return (float)(wsum[0] * invCnt) + 1e-8f;
}

__device__ __forceinline__ float quant_w(float w, float scale) {
  float r = rintf(w / scale);               // round-half-even == jnp.round
  r = fminf(1.f, fmaxf(-1.f, r));
  return r * scale;
}

// ---------------------------------------------------------------------------
__global__ void zero_acc_kernel(double* acc) {  // <<<1,512>>>
  if (threadIdx.x < ACC_DOUBLES) acc[threadIdx.x] = 0.0;
}

// ---------------------------------------------------------------------------
// Parallel sum(|w|), grid = (64, 4), block = 256, atomicAdd per layer.
// ---------------------------------------------------------------------------
__global__ __launch_bounds__(256) void wabs_kernel(
    const float* __restrict__ w1, const float* __restrict__ w2,
    const float* __restrict__ w3, const float* __restrict__ w4,
    double* __restrict__ wsum) {
  int layer = blockIdx.y;
  const float* w; int cnt;
  if      (layer == 0) { w = w1; cnt = 32  * 1   * 10; }
  else if (layer == 1) { w = w2; cnt = 64  * 32  * 8;  }
  else if (layer == 2) { w = w3; cnt = 128 * 64  * 8;  }
  else                 { w = w4; cnt = 256 * 128 * 8;  }

  double s = 0.0;
  for (int i = blockIdx.x * 256 + threadIdx.x; i < cnt; i += gridDim.x * 256)
    s += (double)fabsf(w[i]);
  #pragma unroll
  for (int o = 32; o > 0; o >>= 1) s += __shfl_down(s, o, 64);
  __shared__ double red[4];
  if ((threadIdx.x & 63) == 0) red[threadIdx.x >> 6] = s;
  __syncthreads();
  if (threadIdx.x == 0)
    atomicAdd(&wsum[layer], red[0] + red[1] + red[2] + red[3]);
}

// ---------------------------------------------------------------------------
// Block 1 conv: cin=1, cout=32, k=10, s=5, pad=5. 8 cout per thread, 1 l each.
// ---------------------------------------------------------------------------
__global__ __launch_bounds__(256) void conv1_kernel(
    const float* __restrict__ x, const float* __restrict__ w,
    const double* __restrict__ wsum, double invCnt,
    float* __restrict__ out, double* __restrict__ acc_b,
    int Lin, int Lout, int Pout) {
  const int CPT = 8, K = 10, S = 5;
  int n  = blockIdx.z;
  int co0 = blockIdx.y * CPT;
  int l  = blockIdx.x * 256 + threadIdx.x;

  __shared__ float wlds[CPT * K];
  if (threadIdx.x < CPT * K) {
    float scale = quant_scale(wsum, invCnt);
    wlds[threadIdx.x] = quant_w(w[co0 * K + threadIdx.x], scale);
  }
  __syncthreads();

  float accv[CPT];
  #pragma unroll
  for (int j = 0; j < CPT; ++j) accv[j] = 0.f;

  if (l < Lout) {
    const float* ip = x + (size_t)n * Lin;
    int base = l * S - 5;
    float win[K];
    #pragma unroll
    for (int t = 0; t < K; ++t) {
      int idx = base + t;
      win[t] = (idx >= 0 && idx < Lin) ? ip[idx] : 0.f;
    }
    #pragma unroll
    for (int j = 0; j < CPT; ++j)
      #pragma unroll
      for (int t = 0; t < K; ++t)
        accv[j] = fmaf(win[t], wlds[j * K + t], accv[j]);
    #pragma unroll
    for (int j = 0; j < CPT; ++j)
      out[((size_t)n * 32 + co0 + j) * Pout + l] = accv[j];
  }

  double s = 0.0, s2 = 0.0;
  if (l < Lout) {
    #pragma unroll
    for (int j = 0; j < CPT; ++j) { double v = accv[j]; s += v; s2 += v * v; }
  }
  block_reduce_acc(s, s2, acc_b + 2 * n);
}

// ---------------------------------------------------------------------------
// Blocks 2-4 conv: k=8, s=4, pad=4. CPT=8 cout x LPT l per thread.
// Fast path: register double-buffer prefetch of the next ci's window so L2
// latency hides under the FMA block. LPT per layer picks grid parallelism:
// L2: LPT=4, L3: LPT=2, L4: LPT=1 (small L needs more blocks).
// ---------------------------------------------------------------------------
template <int CIN, int COUT, int LPT>
__global__ __launch_bounds__(256, 4) void conv8_kernel(
    const float* __restrict__ in, const float* __restrict__ w,
    const double* __restrict__ wsum, double invCnt,
    float* __restrict__ out, double* __restrict__ acc_b,
    int Lin, int Pin, int Lout, int Pout) {
  const int K = 8, S = 4, CPT = 8;
  const int WIN = (LPT - 1) * S + K;   // floats: 8 / 12 / 20
  const int W4  = WIN / 4;             // float4s: 2 / 3 / 5

  int n   = blockIdx.z;
  int co0 = blockIdx.y * CPT;
  int l0  = (blockIdx.x * 256 + threadIdx.x) * LPT;

  __shared__ float wlds[CPT * CIN * K];
  {
    float scale = quant_scale(wsum, invCnt);
    for (int i = threadIdx.x; i < CPT * CIN * K; i += 256)
      wlds[i] = quant_w(w[(size_t)co0 * CIN * K + i], scale);
  }
  __syncthreads();

  float accv[CPT][LPT];
  #pragma unroll
  for (int j = 0; j < CPT; ++j)
    #pragma unroll
    for (int r = 0; r < LPT; ++r) accv[j][r] = 0.f;

  bool any = (l0 < Lout);
  if (any) {
    const float* inb = in + (size_t)n * CIN * Pin;
    int base0 = l0 * S - 4;  // multiple of 4 floats (16B) by construction
    bool fast = (base0 >= 0) && (base0 + WIN <= Lin);
    if (fast) {
      const float* rowp = inb + base0;
      float4 cur[W4];
      #pragma unroll
      for (int q = 0; q < W4; ++q)
        cur[q] = reinterpret_cast<const float4*>(rowp)[q];
      for (int ci = 0; ci < CIN; ++ci) {
        // prefetch next row's window (address clamped so load is unconditional)
        const float* nrow = rowp + ((ci + 1 < CIN) ? Pin : 0);
        float4 nxt[W4];
        #pragma unroll
        for (int q = 0; q < W4; ++q)
          nxt[q] = reinterpret_cast<const float4*>(nrow)[q];

        float win[WIN];
        #pragma unroll
        for (int q = 0; q < W4; ++q) {
          win[4 * q + 0] = cur[q].x; win[4 * q + 1] = cur[q].y;
          win[4 * q + 2] = cur[q].z; win[4 * q + 3] = cur[q].w;
        }
        #pragma unroll
        for (int j = 0; j < CPT; ++j) {
          const float* wp = &wlds[(j * CIN + ci) * K];
          #pragma unroll
          for (int r = 0; r < LPT; ++r)
            #pragma unroll
            for (int t = 0; t < K; ++t)
              accv[j][r] = fmaf(win[r * S + t], wp[t], accv[j][r]);
        }
        #pragma unroll
        for (int q = 0; q < W4; ++q) cur[q] = nxt[q];
        rowp = nrow;
      }
    } else {
      for (int ci = 0; ci < CIN; ++ci) {
        const float* ip = inb + (size_t)ci * Pin;
        float win[WIN];
        #pragma unroll
        for (int q = 0; q < WIN; ++q) {
          int idx = base0 + q;
          win[q] = (idx >= 0 && idx < Lin) ? ip[idx] : 0.f;
        }
        #pragma unroll
        for (int j = 0; j < CPT; ++j) {
          const float* wp = &wlds[(j * CIN + ci) * K];
          #pragma unroll
          for (int r = 0; r < LPT; ++r)
            #pragma unroll
            for (int t = 0; t < K; ++t)
              accv[j][r] = fmaf(win[r * S + t], wp[t], accv[j][r]);
        }
      }
    }
    if (l0 + LPT <= Lout) {
      #pragma unroll
      for (int j = 0; j < CPT; ++j) {
        float* op = out + ((size_t)n * COUT + co0 + j) * Pout + l0;
        if constexpr (LPT == 4) {
          *reinterpret_cast<float4*>(op) =
              make_float4(accv[j][0], accv[j][1], accv[j][2], accv[j][3]);
        } else if constexpr (LPT == 2) {
          *reinterpret_cast<float2*>(op) = make_float2(accv[j][0], accv[j][1]);
        } else {
          *op = accv[j][0];
        }
      }
    } else {
      #pragma unroll
      for (int j = 0; j < CPT; ++j)
        #pragma unroll
        for (int r = 0; r < LPT; ++r)
          if (l0 + r < Lout)
            out[((size_t)n * COUT + co0 + j) * Pout + l0 + r] = accv[j][r];
    }
  }

  double s = 0.0, s2 = 0.0;
  if (any) {
    #pragma unroll
    for (int j = 0; j < CPT; ++j)
      #pragma unroll
      for (int r = 0; r < LPT; ++r)
        if (l0 + r < Lout) { double v = accv[j][r]; s += v; s2 += v * v; }
  }
  block_reduce_acc(s, s2, acc_b + 2 * n);
}

// ---------------------------------------------------------------------------
// LayerNorm + snake, in place, float4-vectorized (4 l per thread).
// grid: (ceil(L/1024), C, NC)
// ---------------------------------------------------------------------------
__global__ __launch_bounds__(256) void norm_kernel(
    float* __restrict__ y, const double* __restrict__ acc_b,
    const float* __restrict__ g, const float* __restrict__ b,
    const float* __restrict__ a, const float* __restrict__ p,
    int L, int P, double invCount) {
  int n = blockIdx.z;
  int c = blockIdx.y;
  int l0 = (blockIdx.x * 256 + threadIdx.x) * 4;
  if (l0 >= L) return;
  double sd  = acc_b[2 * n];
  double s2d = acc_b[2 * n + 1];
  double mu_d = sd * invCount;
  float mu  = (float)mu_d;
  float var = (float)(s2d * invCount - mu_d * mu_d);
  float rs  = rsqrtf(var + EPS_GN);
  float gc = g[c], bc = b[c], ac = a[c], pc = p[c];
  float grs = rs * gc;
  size_t base = ((size_t)n * gridDim.y + c) * P;
  if (l0 + 4 <= L) {
    float4 v = *reinterpret_cast<const float4*>(y + base + l0);
    float4 o;
    {
      float z = (v.x - mu) * grs + bc; float sv = __sinf(fmaf(ac, z, pc)); o.x = z + sv * sv / ac;
    }{
      float z = (v.y - mu) * grs + bc; float sv = __sinf(fmaf(ac, z, pc)); o.y = z + sv * sv / ac;
    }{
      float z = (v.z - mu) * grs + bc; float sv = __sinf(fmaf(ac, z, pc)); o.z = z + sv * sv / ac;
    }{
      float z = (v.w - mu) * grs + bc; float sv = __sinf(fmaf(ac, z, pc)); o.w = z + sv * sv / ac;
    }
    *reinterpret_cast<float4*>(y + base + l0) = o;
  } else {
    for (int r = 0; r < 4 && l0 + r < L; ++r) {
      float v = y[base + l0 + r];
      float z = (v - mu) * grs + bc;
      float sv = __sinf(fmaf(ac, z, pc));
      y[base + l0 + r] = z + sv * sv / ac;
    }
  }
}

// ---------------------------------------------------------------------------
// Final block: norm + snake + NCH->NHC transpose into d_out (pre-offset).
// grid: (L, 1, NC), block: 256 (=C)
// ---------------------------------------------------------------------------
__global__ __launch_bounds__(256) void norm4t_kernel(
    const float* __restrict__ y, const double* __restrict__ acc_b,
    const float* __restrict__ g, const float* __restrict__ b,
    const float* __restrict__ a, const float* __restrict__ p,
    float* __restrict__ out, int L, int P, double invCount) {
  int n = blockIdx.z;
  int l = blockIdx.x;
  int c = threadIdx.x;
  double sd  = acc_b[2 * n];
  double s2d = acc_b[2 * n + 1];
  double mu_d = sd * invCount;
  float mu  = (float)mu_d;
  float var = (float)(s2d * invCount - mu_d * mu_d);
  float rs  = rsqrtf(var + EPS_GN);
  float v  = y[((size_t)n * 256 + c) * P + l];
  float z  = (v - mu) * rs * g[c] + b[c];
  float ac = a[c];
  float sv = __sinf(fmaf(ac, z, p[c]));
  out[((size_t)n * L + l) * 256 + c] = z + sv * sv / ac;
}

// ---------------------------------------------------------------------------
extern "C" void kernel_launch(void* const* d_in, const int* in_sizes, int n_in,
                              void* d_out, int out_size, void* d_ws, size_t ws_size,
                              hipStream_t stream) {
  const float* x  = (const float*)d_in[0];
  const float* w1 = (const float*)d_in[1];
  const float* g1 = (const float*)d_in[2];
  const float* b1 = (const float*)d_in[3];
  const float* a1 = (const float*)d_in[4];
  const float* p1 = (const float*)d_in[5];
  const float* w2 = (const float*)d_in[6];
  const float* g2 = (const float*)d_in[7];
  const float* b2 = (const float*)d_in[8];
  const float* a2 = (const float*)d_in[9];
  const float* p2 = (const float*)d_in[10];
  const float* w3 = (const float*)d_in[11];
  const float* g3 = (const float*)d_in[12];
  const float* b3 = (const float*)d_in[13];
  const float* a3 = (const float*)d_in[14];
  const float* p3 = (const float*)d_in[15];
  const float* w4 = (const float*)d_in[16];
  const float* g4 = (const float*)d_in[17];
  const float* b4 = (const float*)d_in[18];
  const float* a4 = (const float*)d_in[19];
  const float* p4 = (const float*)d_in[20];
  float* out = (float*)d_out;
  char* ws = (char*)d_ws;

  const int N  = 32;
  const int L0 = 320000;
  const int L1 = 64001, P1 = 64004;
  const int L2 = 16001, P2 = 16004;
  const int L3 = 4001,  P3 = 4004;
  const int L4 = 1001,  P4 = 1004;

  const double ic1 = 1.0 / (32.0  * 1.0   * 10.0);
  const double ic2 = 1.0 / (64.0  * 32.0  * 8.0);
  const double ic3 = 1.0 / (128.0 * 64.0  * 8.0);
  const double ic4 = 1.0 / (256.0 * 128.0 * 8.0);

  double* acc  = (double*)ws;        // 256 doubles: stats
  double* wsum = acc + 256;          // 4 doubles: sum|w|
  const size_t fixedEnd = 4096;

  const size_t aPer = (size_t)32 * P1;          // layer1 out (>= layer3 out)
  const size_t bPer = (size_t)64 * P2;          // layer2 out (>= layer4 out)
  const size_t perSampleBytes = (aPer + bPer) * 4;

  int NC = (ws_size > fixedEnd) ? (int)((ws_size - fixedEnd) / perSampleBytes) : 0;
  if (NC < 1) NC = 1;
  if (NC > N) NC = N;

  float* bufA = (float*)(ws + fixedEnd);
  float* bufB = bufA + aPer * NC;

  hipLaunchKernelGGL(zero_acc_kernel, dim3(1), dim3(512), 0, stream, acc);
  hipLaunchKernelGGL(wabs_kernel, dim3(64, 4), dim3(256), 0, stream,
                     w1, w2, w3, w4, wsum);

  for (int nb = 0; nb < N; nb += NC) {
    int nc = (N - nb < NC) ? (N - nb) : NC;
    const float* xc = x + (size_t)nb * L0;

    // block 1
    hipLaunchKernelGGL(conv1_kernel, dim3((L1 + 255) / 256, 4, nc), dim3(256), 0, stream,
                       xc, w1, wsum + 0, ic1, bufA, acc + 0 + 2 * nb, L0, L1, P1);
    hipLaunchKernelGGL(norm_kernel, dim3((L1 + 1023) / 1024, 32, nc), dim3(256), 0, stream,
                       bufA, acc + 0 + 2 * nb, g1, b1, a1, p1, L1, P1,
                       1.0 / (32.0 * (double)L1));
    // block 2: LPT=4 -> blocks.x = 16
    hipLaunchKernelGGL((conv8_kernel<32, 64, 4>), dim3((L2 + 1023) / 1024, 8, nc), dim3(256), 0, stream,
                       bufA, w2, wsum + 1, ic2, bufB, acc + 64 + 2 * nb, L1, P1, L2, P2);
    hipLaunchKernelGGL(norm_kernel, dim3((L2 + 1023) / 1024, 64, nc), dim3(256), 0, stream,
                       bufB, acc + 64 + 2 * nb, g2, b2, a2, p2, L2, P2,
                       1.0 / (64.0 * (double)L2));
    // block 3: LPT=2 -> blocks.x = 8
    hipLaunchKernelGGL((conv8_kernel<64, 128, 2>), dim3((L3 + 511) / 512, 16, nc), dim3(256), 0, stream,
                       bufB, w3, wsum + 2, ic3, bufA, acc + 128 + 2 * nb, L2, P2, L3, P3);
    hipLaunchKernelGGL(norm_kernel, dim3((L3 + 1023) / 1024, 128, nc), dim3(256), 0, stream,
                       bufA, acc + 128 + 2 * nb, g3, b3, a3, p3, L3, P3,
                       1.0 / (128.0 * (double)L3));
    // block 4: LPT=1 -> blocks.x = 4 (+ fused transpose after)
    hipLaunchKernelGGL((conv8_kernel<128, 256, 1>), dim3((L4 + 255) / 256, 32, nc), dim3(256), 0, stream,
                       bufA, w4, wsum + 3, ic4, bufB, acc + 192 + 2 * nb, L3, P3, L4, P4);
    hipLaunchKernelGGL(norm4t_kernel, dim3(L4, 1, nc), dim3(256), 0, stream,
                       bufB, acc + 192 + 2 * nb, g4, b4, a4, p4,
                       out + (size_t)nb * L4 * 256, L4, P4,
                       1.0 / (256.0 * (double)L4));
  }
}

// Round 11
// 1197.122 us; speedup vs baseline: 1.7833x; 1.7833x over previous
//
#include <hip/hip_runtime.h>
#include <hip/hip_bf16.h>
#include <math.h>

#define EPS_GN 1e-5f
#define ACC_DOUBLES 260

typedef __attribute__((ext_vector_type(8))) short bf16x8;   // 8 bf16 (4 VGPR)
typedef __attribute__((ext_vector_type(4))) float f32x4;    // MFMA acc

// ---------------------------------------------------------------------------
__device__ __forceinline__ void block_reduce_acc(double s, double s2, double* accn) {
  #pragma unroll
  for (int o = 32; o > 0; o >>= 1) {
    s  += __shfl_down(s, o, 64);
    s2 += __shfl_down(s2, o, 64);
  }
  __shared__ double red[8];
  int wv = threadIdx.x >> 6;
  if ((threadIdx.x & 63) == 0) { red[wv] = s; red[4 + wv] = s2; }
  __syncthreads();
  if (threadIdx.x == 0) {
    double ts = red[0] + red[1] + red[2] + red[3];
    double t2 = red[4] + red[5] + red[6] + red[7];
    atomicAdd(&accn[0], ts);
    atomicAdd(&accn[1], t2);
  }
}

__device__ __forceinline__ float quant_scale(const double* wsum, double invCnt) {
  return (float)(wsum[0] * invCnt) + 1e-8f;
}

__device__ __forceinline__ float quant_w(float w, float scale) {
  float r = rintf(w / scale);               // round-half-even == jnp.round
  r = fminf(1.f, fmaxf(-1.f, r));
  return r * scale;
}

__device__ __forceinline__ unsigned short f2bf(float v) {
  union { __hip_bfloat16 h; unsigned short u; } cv;
  cv.h = __float2bfloat16(v);
  return cv.u;
}

// ---------------------------------------------------------------------------
__global__ void zero_acc_kernel(double* acc) {  // <<<1,512>>>
  if (threadIdx.x < ACC_DOUBLES) acc[threadIdx.x] = 0.0;
}

// ---------------------------------------------------------------------------
// Parallel sum(|w|), grid = (64, 4), block = 256, atomicAdd per layer.
// ---------------------------------------------------------------------------
__global__ __launch_bounds__(256) void wabs_kernel(
    const float* __restrict__ w1, const float* __restrict__ w2,
    const float* __restrict__ w3, const float* __restrict__ w4,
    double* __restrict__ wsum) {
  int layer = blockIdx.y;
  const float* w; int cnt;
  if      (layer == 0) { w = w1; cnt = 32  * 1   * 10; }
  else if (layer == 1) { w = w2; cnt = 64  * 32  * 8;  }
  else if (layer == 2) { w = w3; cnt = 128 * 64  * 8;  }
  else                 { w = w4; cnt = 256 * 128 * 8;  }

  double s = 0.0;
  for (int i = blockIdx.x * 256 + threadIdx.x; i < cnt; i += gridDim.x * 256)
    s += (double)fabsf(w[i]);
  #pragma unroll
  for (int o = 32; o > 0; o >>= 1) s += __shfl_down(s, o, 64);
  __shared__ double red[4];
  if ((threadIdx.x & 63) == 0) red[threadIdx.x >> 6] = s;
  __syncthreads();
  if (threadIdx.x == 0)
    atomicAdd(&wsum[layer], red[0] + red[1] + red[2] + red[3]);
}

// ---------------------------------------------------------------------------
// Quantize + convert weights of layers 2-4 to bf16. grid = (64, 3).
// Ternary values {-s,0,+s} -> bf16 is a pure per-layer scale perturbation,
// which LayerNorm cancels exactly.
// ---------------------------------------------------------------------------
__global__ __launch_bounds__(256) void wprep_kernel(
    const float* __restrict__ w2, const float* __restrict__ w3,
    const float* __restrict__ w4, const double* __restrict__ wsum,
    unsigned short* __restrict__ q2, unsigned short* __restrict__ q3,
    unsigned short* __restrict__ q4) {
  int ly = blockIdx.y;
  const float* w; unsigned short* q; int cnt;
  if      (ly == 0) { w = w2; q = q2; cnt = 64  * 32  * 8; }
  else if (ly == 1) { w = w3; q = q3; cnt = 128 * 64  * 8; }
  else              { w = w4; q = q4; cnt = 256 * 128 * 8; }
  float scale = quant_scale(wsum + ly + 1, 1.0 / (double)cnt);
  for (int i = blockIdx.x * 256 + threadIdx.x; i < cnt; i += gridDim.x * 256)
    q[i] = f2bf(quant_w(w[i], scale));
}

// ---------------------------------------------------------------------------
// Block 1 conv (fp32): cin=1, cout=32, k=10, s=5, pad=5.
// ---------------------------------------------------------------------------
__global__ __launch_bounds__(256) void conv1_kernel(
    const float* __restrict__ x, const float* __restrict__ w,
    const double* __restrict__ wsum, double invCnt,
    float* __restrict__ out, double* __restrict__ acc_b,
    int Lin, int Lout, int Pout) {
  const int CPT = 8, K = 10, S = 5;
  int n  = blockIdx.z;
  int co0 = blockIdx.y * CPT;
  int l  = blockIdx.x * 256 + threadIdx.x;

  __shared__ float wlds[CPT * K];
  if (threadIdx.x < CPT * K) {
    float scale = quant_scale(wsum, invCnt);
    wlds[threadIdx.x] = quant_w(w[co0 * K + threadIdx.x], scale);
  }
  __syncthreads();

  float accv[CPT];
  #pragma unroll
  for (int j = 0; j < CPT; ++j) accv[j] = 0.f;

  if (l < Lout) {
    const float* ip = x + (size_t)n * Lin;
    int base = l * S - 5;
    float win[K];
    #pragma unroll
    for (int t = 0; t < K; ++t) {
      int idx = base + t;
      win[t] = (idx >= 0 && idx < Lin) ? ip[idx] : 0.f;
    }
    #pragma unroll
    for (int j = 0; j < CPT; ++j)
      #pragma unroll
      for (int t = 0; t < K; ++t)
        accv[j] = fmaf(win[t], wlds[j * K + t], accv[j]);
    #pragma unroll
    for (int j = 0; j < CPT; ++j)
      out[((size_t)n * 32 + co0 + j) * Pout + l] = accv[j];
  }

  double s = 0.0, s2 = 0.0;
  if (l < Lout) {
    #pragma unroll
    for (int j = 0; j < CPT; ++j) { double v = accv[j]; s += v; s2 += v * v; }
  }
  block_reduce_acc(s, s2, acc_b + 2 * n);
}

// ---------------------------------------------------------------------------
// LayerNorm + snake -> bf16 copy with +4 left shift and zero padding to PB.
// xb row layout: [0,0,0,0, x_0 .. x_{L-1}, 0 ... 0] (PB elems, PB % 8 == 0).
// grid: (ceil(PB/1024), C, nc), 4 elems/thread, 8B stores.
// ---------------------------------------------------------------------------
__global__ __launch_bounds__(256) void norm_bf16_kernel(
    const float* __restrict__ y, const double* __restrict__ acc_b,
    const float* __restrict__ g, const float* __restrict__ b,
    const float* __restrict__ a, const float* __restrict__ p,
    unsigned short* __restrict__ xb,
    int L, int P, int PB, double invCount) {
  int n = blockIdx.z;
  int c = blockIdx.y;
  int i0 = (blockIdx.x * 256 + threadIdx.x) * 4;
  if (i0 >= PB) return;
  double sd  = acc_b[2 * n];
  double s2d = acc_b[2 * n + 1];
  double mu_d = sd * invCount;
  float mu  = (float)mu_d;
  float var = (float)(s2d * invCount - mu_d * mu_d);
  float rs  = rsqrtf(var + EPS_GN);
  float gc = g[c], bc = b[c], ac = a[c], pc = p[c];
  float grs = rs * gc;
  const float* yr = y + ((size_t)n * gridDim.y + c) * P;
  unsigned short* xr = xb + ((size_t)n * gridDim.y + c) * PB;

  unsigned short ov[4];
  #pragma unroll
  for (int r = 0; r < 4; ++r) {
    int l = i0 + r - 4;
    float v = 0.f;
    if (l >= 0 && l < L) {
      float z = (yr[l] - mu) * grs + bc;
      float sv = __sinf(fmaf(ac, z, pc));
      v = z + sv * sv / ac;
    }
    ov[r] = f2bf(v);
  }
  if (i0 + 4 <= PB) {
    union { unsigned short s[4]; uint2 u; } pk;
    pk.s[0] = ov[0]; pk.s[1] = ov[1]; pk.s[2] = ov[2]; pk.s[3] = ov[3];
    *reinterpret_cast<uint2*>(xr + i0) = pk.u;
  } else {
    for (int r = 0; r < 4 && i0 + r < PB; ++r) xr[i0 + r] = ov[r];
  }
}

// ---------------------------------------------------------------------------
// Convs 2-4 as bf16 MFMA implicit GEMM.
//   C[co, l] = sum_k W[co, k] * B[k, l],  k = ci*8 + t,  KT = 8*CIN
//   B[k, l] = xb_row(ci)[4*l + t]   (xb has the +4 pad shift built in)
// Block = 256 thr = 4 waves; tile = 64 couts x 64 l; wave = 16 couts x 64 l.
// A-frag: lane reads 8 consecutive k of its cout row (16B aligned b128).
// B-frag: lane reads 8 consecutive bf16 of one ci row (two 8B loads).
// Same lane->k formula for A and B => correct under any HW k-permutation.
// D layout (m89-verified): row = (lane>>4)*4 + r, col = lane&15.
// No LDS staging, no barriers -> high occupancy; K-loop = KT/32 steps.
// grid: (ceil(Lout/64), COUT/64, nc)
// ---------------------------------------------------------------------------
template <int CIN, int COUT>
__global__ __launch_bounds__(256) void conv_mfma_kernel(
    const unsigned short* __restrict__ xb, const unsigned short* __restrict__ wq,
    float* __restrict__ out, double* __restrict__ acc_b,
    int PBin, int Lout, int Pout) {
  const int KT = CIN * 8;
  int n    = blockIdx.z;
  int lane = threadIdx.x & 63;
  int wv   = threadIdx.x >> 6;
  int grp  = lane >> 4;        // 0..3
  int lr   = lane & 15;        // 0..15
  int co16 = blockIdx.y * 64 + wv * 16;   // wave's cout base
  int lb   = blockIdx.x * 64;             // block's l base

  f32x4 a0 = {0.f, 0.f, 0.f, 0.f};
  f32x4 a1 = {0.f, 0.f, 0.f, 0.f};
  f32x4 a2 = {0.f, 0.f, 0.f, 0.f};
  f32x4 a3 = {0.f, 0.f, 0.f, 0.f};

  const unsigned short* arow = wq + (size_t)(co16 + lr) * KT + grp * 8;
  const unsigned short* xbn  = xb + ((size_t)n * CIN + grp) * PBin;
  int c0 = (lb + lr) * 4;      // window-start element for col (lb+lr)

  #pragma unroll 4
  for (int kk = 0; kk < KT / 32; ++kk) {
    bf16x8 af = *reinterpret_cast<const bf16x8*>(arow + kk * 32);
    const unsigned short* xr = xbn + (size_t)(kk * 4) * PBin;
    union { uint2 u[2]; bf16x8 v; } b0, b1, b2, b3;
    b0.u[0] = *(const uint2*)(xr + c0);       b0.u[1] = *(const uint2*)(xr + c0 + 4);
    b1.u[0] = *(const uint2*)(xr + c0 + 64);  b1.u[1] = *(const uint2*)(xr + c0 + 68);
    b2.u[0] = *(const uint2*)(xr + c0 + 128); b2.u[1] = *(const uint2*)(xr + c0 + 132);
    b3.u[0] = *(const uint2*)(xr + c0 + 192); b3.u[1] = *(const uint2*)(xr + c0 + 196);
    a0 = __builtin_amdgcn_mfma_f32_16x16x32_bf16(af, b0.v, a0, 0, 0, 0);
    a1 = __builtin_amdgcn_mfma_f32_16x16x32_bf16(af, b1.v, a1, 0, 0, 0);
    a2 = __builtin_amdgcn_mfma_f32_16x16x32_bf16(af, b2.v, a2, 0, 0, 0);
    a3 = __builtin_amdgcn_mfma_f32_16x16x32_bf16(af, b3.v, a3, 0, 0, 0);
  }

  double s = 0.0, s2 = 0.0;
  float* ob = out + (size_t)n * COUT * Pout;
  {
    int l = lb + 0 * 16 + lr;
    if (l < Lout) {
      #pragma unroll
      for (int r = 0; r < 4; ++r) {
        float v = a0[r];
        ob[(size_t)(co16 + grp * 4 + r) * Pout + l] = v;
        s += v; s2 += (double)v * v;
      }
    }
  }
  {
    int l = lb + 1 * 16 + lr;
    if (l < Lout) {
      #pragma unroll
      for (int r = 0; r < 4; ++r) {
        float v = a1[r];
        ob[(size_t)(co16 + grp * 4 + r) * Pout + l] = v;
        s += v; s2 += (double)v * v;
      }
    }
  }
  {
    int l = lb + 2 * 16 + lr;
    if (l < Lout) {
      #pragma unroll
      for (int r = 0; r < 4; ++r) {
        float v = a2[r];
        ob[(size_t)(co16 + grp * 4 + r) * Pout + l] = v;
        s += v; s2 += (double)v * v;
      }
    }
  }
  {
    int l = lb + 3 * 16 + lr;
    if (l < Lout) {
      #pragma unroll
      for (int r = 0; r < 4; ++r) {
        float v = a3[r];
        ob[(size_t)(co16 + grp * 4 + r) * Pout + l] = v;
        s += v; s2 += (double)v * v;
      }
    }
  }
  block_reduce_acc(s, s2, acc_b + 2 * n);
}

// ---------------------------------------------------------------------------
// Final block: norm + snake + NCH->NHC transpose into d_out (pre-offset).
// grid: (L, 1, nc), block: 256 (=C)
// ---------------------------------------------------------------------------
__global__ __launch_bounds__(256) void norm4t_kernel(
    const float* __restrict__ y, const double* __restrict__ acc_b,
    const float* __restrict__ g, const float* __restrict__ b,
    const float* __restrict__ a, const float* __restrict__ p,
    float* __restrict__ out, int L, int P, double invCount) {
  int n = blockIdx.z;
  int l = blockIdx.x;
  int c = threadIdx.x;
  double sd  = acc_b[2 * n];
  double s2d = acc_b[2 * n + 1];
  double mu_d = sd * invCount;
  float mu  = (float)mu_d;
  float var = (float)(s2d * invCount - mu_d * mu_d);
  float rs  = rsqrtf(var + EPS_GN);
  float v  = y[((size_t)n * 256 + c) * P + l];
  float z  = (v - mu) * rs * g[c] + b[c];
  float ac = a[c];
  float sv = __sinf(fmaf(ac, z, p[c]));
  out[((size_t)n * L + l) * 256 + c] = z + sv * sv / ac;
}

// ---------------------------------------------------------------------------
extern "C" void kernel_launch(void* const* d_in, const int* in_sizes, int n_in,
                              void* d_out, int out_size, void* d_ws, size_t ws_size,
                              hipStream_t stream) {
  const float* x  = (const float*)d_in[0];
  const float* w1 = (const float*)d_in[1];
  const float* g1 = (const float*)d_in[2];
  const float* b1 = (const float*)d_in[3];
  const float* a1 = (const float*)d_in[4];
  const float* p1 = (const float*)d_in[5];
  const float* w2 = (const float*)d_in[6];
  const float* g2 = (const float*)d_in[7];
  const float* b2 = (const float*)d_in[8];
  const float* a2 = (const float*)d_in[9];
  const float* p2 = (const float*)d_in[10];
  const float* w3 = (const float*)d_in[11];
  const float* g3 = (const float*)d_in[12];
  const float* b3 = (const float*)d_in[13];
  const float* a3 = (const float*)d_in[14];
  const float* p3 = (const float*)d_in[15];
  const float* w4 = (const float*)d_in[16];
  const float* g4 = (const float*)d_in[17];
  const float* b4 = (const float*)d_in[18];
  const float* a4 = (const float*)d_in[19];
  const float* p4 = (const float*)d_in[20];
  float* out = (float*)d_out;
  char* ws = (char*)d_ws;

  const int N  = 32;
  const int L0 = 320000;
  const int L1 = 64001, P1 = 64004;
  const int L2 = 16001, P2 = 16004;
  const int L3 = 4001,  P3 = 4004;
  const int L4 = 1001,  P4 = 1004;
  // bf16 activation pitches: must cover 4*(ceil(Lout/64)*64 - 1) + 8, % 8 == 0
  const int PB1 = 64264;   // >= 4*16063 + 8
  const int PB2 = 16136;   // >= 4*4031  + 8
  const int PB3 = 4104;    // >= 4*1023  + 8

  const double ic1 = 1.0 / (32.0 * 1.0 * 10.0);

  // fixed ws region
  double* acc = (double*)ws;                                   // 260 doubles
  unsigned short* q2 = (unsigned short*)(ws + 4096);           // 16384 bf16
  unsigned short* q3 = (unsigned short*)(ws + 65536);          // 65536 bf16
  unsigned short* q4 = (unsigned short*)(ws + 262144);         // 262144 bf16
  const size_t fixedEnd = 1048576;

  const size_t aPer  = (size_t)32 * P1;    // y1 (>= y3 = 128*P3)
  const size_t bPer  = (size_t)64 * P2;    // y2 (>= y4 = 256*P4)
  const size_t xbPer = (size_t)32 * PB1;   // xb1 (>= xb2 = 64*PB2, xb3 = 128*PB3)
  const size_t perSampleBytes = (aPer + bPer) * 4 + xbPer * 2;  // ~16.4 MB

  int NC = (ws_size > fixedEnd) ? (int)((ws_size - fixedEnd) / perSampleBytes) : 0;
  if (NC < 1) NC = 1;
  if (NC > N) NC = N;

  float* bufA = (float*)(ws + fixedEnd);
  float* bufB = bufA + aPer * NC;
  unsigned short* XB = (unsigned short*)(bufB + bPer * NC);

  hipLaunchKernelGGL(zero_acc_kernel, dim3(1), dim3(512), 0, stream, acc);
  hipLaunchKernelGGL(wabs_kernel, dim3(64, 4), dim3(256), 0, stream,
                     w1, w2, w3, w4, acc + 256);
  hipLaunchKernelGGL(wprep_kernel, dim3(64, 3), dim3(256), 0, stream,
                     w2, w3, w4, acc + 256, q2, q3, q4);

  for (int nb = 0; nb < N; nb += NC) {
    int nc = (N - nb < NC) ? (N - nb) : NC;
    const float* xc = x + (size_t)nb * L0;

    // block 1 (fp32 conv)
    hipLaunchKernelGGL(conv1_kernel, dim3((L1 + 255) / 256, 4, nc), dim3(256), 0, stream,
                       xc, w1, acc + 256, ic1, bufA, acc + 0 + 2 * nb, L0, L1, P1);
    hipLaunchKernelGGL(norm_bf16_kernel, dim3((PB1 + 1023) / 1024, 32, nc), dim3(256), 0, stream,
                       bufA, acc + 0 + 2 * nb, g1, b1, a1, p1, XB, L1, P1, PB1,
                       1.0 / (32.0 * (double)L1));
    // block 2 (MFMA)
    hipLaunchKernelGGL((conv_mfma_kernel<32, 64>), dim3((L2 + 63) / 64, 1, nc), dim3(256), 0, stream,
                       XB, q2, bufB, acc + 64 + 2 * nb, PB1, L2, P2);
    hipLaunchKernelGGL(norm_bf16_kernel, dim3((PB2 + 1023) / 1024, 64, nc), dim3(256), 0, stream,
                       bufB, acc + 64 + 2 * nb, g2, b2, a2, p2, XB, L2, P2, PB2,
                       1.0 / (64.0 * (double)L2));
    // block 3 (MFMA)
    hipLaunchKernelGGL((conv_mfma_kernel<64, 128>), dim3((L3 + 63) / 64, 2, nc), dim3(256), 0, stream,
                       XB, q3, bufA, acc + 128 + 2 * nb, PB2, L3, P3);
    hipLaunchKernelGGL(norm_bf16_kernel, dim3((PB3 + 1023) / 1024, 128, nc), dim3(256), 0, stream,
                       bufA, acc + 128 + 2 * nb, g3, b3, a3, p3, XB, L3, P3, PB3,
                       1.0 / (128.0 * (double)L3));
    // block 4 (MFMA) + fused transpose epilogue
    hipLaunchKernelGGL((conv_mfma_kernel<128, 256>), dim3((L4 + 63) / 64, 4, nc), dim3(256), 0, stream,
                       XB, q4, bufB, acc + 192 + 2 * nb, PB3, L4, P4);
    hipLaunchKernelGGL(norm4t_kernel, dim3(L4, 1, nc), dim3(256), 0, stream,
                       bufB, acc + 192 + 2 * nb, g4, b4, a4, p4,
                       out + (size_t)nb * L4 * 256, L4, P4,
                       1.0 / (256.0 * (double)L4));
  }
}

// Round 12
// 1166.138 us; speedup vs baseline: 1.8307x; 1.0266x over previous
//
#include <hip/hip_runtime.h>
#include <hip/hip_bf16.h>
#include <math.h>

#define EPS_GN 1e-5f
#define ACC_DOUBLES 260

typedef __attribute__((ext_vector_type(8))) short bf16x8;   // 8 bf16 (4 VGPR)
typedef __attribute__((ext_vector_type(4))) float f32x4;    // MFMA acc

// ---------------------------------------------------------------------------
__device__ __forceinline__ void block_reduce_acc(double s, double s2, double* accn) {
  #pragma unroll
  for (int o = 32; o > 0; o >>= 1) {
    s  += __shfl_down(s, o, 64);
    s2 += __shfl_down(s2, o, 64);
  }
  __shared__ double red[8];
  int wv = threadIdx.x >> 6;
  if ((threadIdx.x & 63) == 0) { red[wv] = s; red[4 + wv] = s2; }
  __syncthreads();
  if (threadIdx.x == 0) {
    double ts = red[0] + red[1] + red[2] + red[3];
    double t2 = red[4] + red[5] + red[6] + red[7];
    atomicAdd(&accn[0], ts);
    atomicAdd(&accn[1], t2);
  }
}

__device__ __forceinline__ float quant_scale(const double* wsum, double invCnt) {
  return (float)(wsum[0] * invCnt) + 1e-8f;
}

__device__ __forceinline__ float quant_w(float w, float scale) {
  float r = rintf(w / scale);               // round-half-even == jnp.round
  r = fminf(1.f, fmaxf(-1.f, r));
  return r * scale;
}

__device__ __forceinline__ unsigned short f2bf(float v) {
  union { __hip_bfloat16 h; unsigned short u; } cv;
  cv.h = __float2bfloat16(v);
  return cv.u;
}

__device__ __forceinline__ float bf2f(unsigned short u) {
  union { unsigned int i; float f; } cv;
  cv.i = ((unsigned int)u) << 16;
  return cv.f;
}

// element loaders for the templated norm kernel
__device__ __forceinline__ float loadS(const float* p) { return *p; }
__device__ __forceinline__ float loadS(const unsigned short* p) { return bf2f(*p); }
__device__ __forceinline__ void load4v(const float* p, float* v) {
  float4 t = *reinterpret_cast<const float4*>(p);
  v[0] = t.x; v[1] = t.y; v[2] = t.z; v[3] = t.w;
}
__device__ __forceinline__ void load4v(const unsigned short* p, float* v) {
  union { unsigned short s[4]; uint2 u; } t;
  t.u = *reinterpret_cast<const uint2*>(p);
  v[0] = bf2f(t.s[0]); v[1] = bf2f(t.s[1]); v[2] = bf2f(t.s[2]); v[3] = bf2f(t.s[3]);
}

// ---------------------------------------------------------------------------
__global__ void zero_acc_kernel(double* acc) {  // <<<1,512>>>
  if (threadIdx.x < ACC_DOUBLES) acc[threadIdx.x] = 0.0;
}

// ---------------------------------------------------------------------------
// Parallel sum(|w|), grid = (64, 4), block = 256, atomicAdd per layer.
// ---------------------------------------------------------------------------
__global__ __launch_bounds__(256) void wabs_kernel(
    const float* __restrict__ w1, const float* __restrict__ w2,
    const float* __restrict__ w3, const float* __restrict__ w4,
    double* __restrict__ wsum) {
  int layer = blockIdx.y;
  const float* w; int cnt;
  if      (layer == 0) { w = w1; cnt = 32  * 1   * 10; }
  else if (layer == 1) { w = w2; cnt = 64  * 32  * 8;  }
  else if (layer == 2) { w = w3; cnt = 128 * 64  * 8;  }
  else                 { w = w4; cnt = 256 * 128 * 8;  }

  double s = 0.0;
  for (int i = blockIdx.x * 256 + threadIdx.x; i < cnt; i += gridDim.x * 256)
    s += (double)fabsf(w[i]);
  #pragma unroll
  for (int o = 32; o > 0; o >>= 1) s += __shfl_down(s, o, 64);
  __shared__ double red[4];
  if ((threadIdx.x & 63) == 0) red[threadIdx.x >> 6] = s;
  __syncthreads();
  if (threadIdx.x == 0)
    atomicAdd(&wsum[layer], red[0] + red[1] + red[2] + red[3]);
}

// ---------------------------------------------------------------------------
// Quantize + convert weights of layers 2-4 to bf16. grid = (64, 3).
// Ternary {-s,0,+s} -> bf16 is a pure per-layer scale perturbation, which
// the following LayerNorm cancels exactly.
// ---------------------------------------------------------------------------
__global__ __launch_bounds__(256) void wprep_kernel(
    const float* __restrict__ w2, const float* __restrict__ w3,
    const float* __restrict__ w4, const double* __restrict__ wsum,
    unsigned short* __restrict__ q2, unsigned short* __restrict__ q3,
    unsigned short* __restrict__ q4) {
  int ly = blockIdx.y;
  const float* w; unsigned short* q; int cnt;
  if      (ly == 0) { w = w2; q = q2; cnt = 64  * 32  * 8; }
  else if (ly == 1) { w = w3; q = q3; cnt = 128 * 64  * 8; }
  else              { w = w4; q = q4; cnt = 256 * 128 * 8; }
  float scale = quant_scale(wsum + ly + 1, 1.0 / (double)cnt);
  for (int i = blockIdx.x * 256 + threadIdx.x; i < cnt; i += gridDim.x * 256)
    q[i] = f2bf(quant_w(w[i], scale));
}

// ---------------------------------------------------------------------------
// Block 1 conv: cin=1, cout=32, k=10, s=5, pad=5.
// LDS-staged input (coalesced float4 global loads), bf16 output.
// Stats from fp32 accumulators (bit-identical to before).
// grid: (ceil(L1/256), 4, nc)
// ---------------------------------------------------------------------------
__global__ __launch_bounds__(256) void conv1_kernel(
    const float* __restrict__ x, const float* __restrict__ w,
    const double* __restrict__ wsum, double invCnt,
    unsigned short* __restrict__ out, double* __restrict__ acc_b,
    int Lin, int Lout, int Pout) {
  const int CPT = 8, K = 10, S = 5;
  __shared__ __align__(16) float xin[1300];   // 256*5+10 = 1290 (+align slack)
  __shared__ float wlds[CPT * K];

  int n   = blockIdx.z;
  int co0 = blockIdx.y * CPT;
  int l0  = blockIdx.x * 256;
  int l   = l0 + threadIdx.x;

  if (threadIdx.x < CPT * K) {
    float scale = quant_scale(wsum, invCnt);
    wlds[threadIdx.x] = quant_w(w[co0 * K + threadIdx.x], scale);
  }

  // stage x[wstart .. wstart+1290) via aligned float4 loads
  const float* ip = x + (size_t)n * Lin;
  int wstart = l0 * S - 5;
  int astart = wstart & ~3;        // 16B-aligned floor (can be negative)
  int off    = wstart - astart;    // 0..3
  for (int i = threadIdx.x; i < 324; i += 256) {
    int gi = astart + i * 4;
    float4 v;
    if (gi >= 0 && gi + 4 <= Lin) {
      v = *reinterpret_cast<const float4*>(ip + gi);
    } else {
      v.x = (gi + 0 >= 0 && gi + 0 < Lin) ? ip[gi + 0] : 0.f;
      v.y = (gi + 1 >= 0 && gi + 1 < Lin) ? ip[gi + 1] : 0.f;
      v.z = (gi + 2 >= 0 && gi + 2 < Lin) ? ip[gi + 2] : 0.f;
      v.w = (gi + 3 >= 0 && gi + 3 < Lin) ? ip[gi + 3] : 0.f;
    }
    *reinterpret_cast<float4*>(xin + i * 4) = v;
  }
  __syncthreads();

  float accv[CPT];
  #pragma unroll
  for (int j = 0; j < CPT; ++j) accv[j] = 0.f;

  if (l < Lout) {
    float win[K];
    int base = threadIdx.x * S + off;
    #pragma unroll
    for (int t = 0; t < K; ++t) win[t] = xin[base + t];
    #pragma unroll
    for (int j = 0; j < CPT; ++j)
      #pragma unroll
      for (int t = 0; t < K; ++t)
        accv[j] = fmaf(win[t], wlds[j * K + t], accv[j]);
    #pragma unroll
    for (int j = 0; j < CPT; ++j)
      out[((size_t)n * 32 + co0 + j) * Pout + l] = f2bf(accv[j]);
  }

  double s = 0.0, s2 = 0.0;
  if (l < Lout) {
    #pragma unroll
    for (int j = 0; j < CPT; ++j) { double v = accv[j]; s += v; s2 += v * v; }
  }
  block_reduce_acc(s, s2, acc_b + 2 * n);
}

// ---------------------------------------------------------------------------
// LayerNorm + snake -> bf16 copy with +4 left shift and zero padding to PB.
// Input T = float (layers 2,3) or unsigned short (bf16, layer 1).
// xb row layout: [0,0,0,0, x_0 .. x_{L-1}, 0 ... 0] (PB elems, PB % 8 == 0).
// grid: (ceil(PB/1024), C, nc), 4 elems/thread, 8B stores.
// ---------------------------------------------------------------------------
template <typename T>
__global__ __launch_bounds__(256) void norm_bf16_kernel(
    const T* __restrict__ y, const double* __restrict__ acc_b,
    const float* __restrict__ g, const float* __restrict__ b,
    const float* __restrict__ a, const float* __restrict__ p,
    unsigned short* __restrict__ xb,
    int L, int P, int PB, double invCount) {
  int n = blockIdx.z;
  int c = blockIdx.y;
  int i0 = (blockIdx.x * 256 + threadIdx.x) * 4;
  if (i0 >= PB) return;
  double sd  = acc_b[2 * n];
  double s2d = acc_b[2 * n + 1];
  double mu_d = sd * invCount;
  float mu  = (float)mu_d;
  float var = (float)(s2d * invCount - mu_d * mu_d);
  float rs  = rsqrtf(var + EPS_GN);
  float gc = g[c], bc = b[c], ac = a[c], pc = p[c];
  float grs = rs * gc;
  const T* yr = y + ((size_t)n * gridDim.y + c) * P;
  unsigned short* xr = xb + ((size_t)n * gridDim.y + c) * PB;

  int lstart = i0 - 4;
  float vin[4];
  bool val[4];
  if (lstart >= 0 && lstart + 4 <= L) {
    load4v(yr + lstart, vin);
    val[0] = val[1] = val[2] = val[3] = true;
  } else {
    #pragma unroll
    for (int r = 0; r < 4; ++r) {
      int lr = lstart + r;
      val[r] = (lr >= 0 && lr < L);
      vin[r] = val[r] ? loadS(yr + lr) : 0.f;
    }
  }

  unsigned short ov[4];
  #pragma unroll
  for (int r = 0; r < 4; ++r) {
    float v = 0.f;
    if (val[r]) {
      float z = (vin[r] - mu) * grs + bc;
      float sv = __sinf(fmaf(ac, z, pc));
      v = z + sv * sv / ac;
    }
    ov[r] = f2bf(v);
  }
  if (i0 + 4 <= PB) {
    union { unsigned short s[4]; uint2 u; } pk;
    pk.s[0] = ov[0]; pk.s[1] = ov[1]; pk.s[2] = ov[2]; pk.s[3] = ov[3];
    *reinterpret_cast<uint2*>(xr + i0) = pk.u;
  } else {
    for (int r = 0; r < 4 && i0 + r < PB; ++r) xr[i0 + r] = ov[r];
  }
}

// ---------------------------------------------------------------------------
// Convs 2-4 as bf16 MFMA implicit GEMM (unchanged from round 10; verified).
// grid: (ceil(Lout/64), COUT/64, nc)
// ---------------------------------------------------------------------------
template <int CIN, int COUT>
__global__ __launch_bounds__(256) void conv_mfma_kernel(
    const unsigned short* __restrict__ xb, const unsigned short* __restrict__ wq,
    float* __restrict__ out, double* __restrict__ acc_b,
    int PBin, int Lout, int Pout) {
  const int KT = CIN * 8;
  int n    = blockIdx.z;
  int lane = threadIdx.x & 63;
  int wv   = threadIdx.x >> 6;
  int grp  = lane >> 4;        // 0..3
  int lr   = lane & 15;        // 0..15
  int co16 = blockIdx.y * 64 + wv * 16;   // wave's cout base
  int lb   = blockIdx.x * 64;             // block's l base

  f32x4 a0 = {0.f, 0.f, 0.f, 0.f};
  f32x4 a1 = {0.f, 0.f, 0.f, 0.f};
  f32x4 a2 = {0.f, 0.f, 0.f, 0.f};
  f32x4 a3 = {0.f, 0.f, 0.f, 0.f};

  const unsigned short* arow = wq + (size_t)(co16 + lr) * KT + grp * 8;
  const unsigned short* xbn  = xb + ((size_t)n * CIN + grp) * PBin;
  int c0 = (lb + lr) * 4;      // window-start element for col (lb+lr)

  #pragma unroll 4
  for (int kk = 0; kk < KT / 32; ++kk) {
    bf16x8 af = *reinterpret_cast<const bf16x8*>(arow + kk * 32);
    const unsigned short* xr = xbn + (size_t)(kk * 4) * PBin;
    union { uint2 u[2]; bf16x8 v; } b0, b1, b2, b3;
    b0.u[0] = *(const uint2*)(xr + c0);       b0.u[1] = *(const uint2*)(xr + c0 + 4);
    b1.u[0] = *(const uint2*)(xr + c0 + 64);  b1.u[1] = *(const uint2*)(xr + c0 + 68);
    b2.u[0] = *(const uint2*)(xr + c0 + 128); b2.u[1] = *(const uint2*)(xr + c0 + 132);
    b3.u[0] = *(const uint2*)(xr + c0 + 192); b3.u[1] = *(const uint2*)(xr + c0 + 196);
    a0 = __builtin_amdgcn_mfma_f32_16x16x32_bf16(af, b0.v, a0, 0, 0, 0);
    a1 = __builtin_amdgcn_mfma_f32_16x16x32_bf16(af, b1.v, a1, 0, 0, 0);
    a2 = __builtin_amdgcn_mfma_f32_16x16x32_bf16(af, b2.v, a2, 0, 0, 0);
    a3 = __builtin_amdgcn_mfma_f32_16x16x32_bf16(af, b3.v, a3, 0, 0, 0);
  }

  double s = 0.0, s2 = 0.0;
  float* ob = out + (size_t)n * COUT * Pout;
  {
    int l = lb + 0 * 16 + lr;
    if (l < Lout) {
      #pragma unroll
      for (int r = 0; r < 4; ++r) {
        float v = a0[r];
        ob[(size_t)(co16 + grp * 4 + r) * Pout + l] = v;
        s += v; s2 += (double)v * v;
      }
    }
  }
  {
    int l = lb + 1 * 16 + lr;
    if (l < Lout) {
      #pragma unroll
      for (int r = 0; r < 4; ++r) {
        float v = a1[r];
        ob[(size_t)(co16 + grp * 4 + r) * Pout + l] = v;
        s += v; s2 += (double)v * v;
      }
    }
  }
  {
    int l = lb + 2 * 16 + lr;
    if (l < Lout) {
      #pragma unroll
      for (int r = 0; r < 4; ++r) {
        float v = a2[r];
        ob[(size_t)(co16 + grp * 4 + r) * Pout + l] = v;
        s += v; s2 += (double)v * v;
      }
    }
  }
  {
    int l = lb + 3 * 16 + lr;
    if (l < Lout) {
      #pragma unroll
      for (int r = 0; r < 4; ++r) {
        float v = a3[r];
        ob[(size_t)(co16 + grp * 4 + r) * Pout + l] = v;
        s += v; s2 += (double)v * v;
      }
    }
  }
  block_reduce_acc(s, s2, acc_b + 2 * n);
}

// ---------------------------------------------------------------------------
// Final block: norm + snake + NCH->NHC transpose into d_out (pre-offset).
// grid: (L, 1, nc), block: 256 (=C)
// ---------------------------------------------------------------------------
__global__ __launch_bounds__(256) void norm4t_kernel(
    const float* __restrict__ y, const double* __restrict__ acc_b,
    const float* __restrict__ g, const float* __restrict__ b,
    const float* __restrict__ a, const float* __restrict__ p,
    float* __restrict__ out, int L, int P, double invCount) {
  int n = blockIdx.z;
  int l = blockIdx.x;
  int c = threadIdx.x;
  double sd  = acc_b[2 * n];
  double s2d = acc_b[2 * n + 1];
  double mu_d = sd * invCount;
  float mu  = (float)mu_d;
  float var = (float)(s2d * invCount - mu_d * mu_d);
  float rs  = rsqrtf(var + EPS_GN);
  float v  = y[((size_t)n * 256 + c) * P + l];
  float z  = (v - mu) * rs * g[c] + b[c];
  float ac = a[c];
  float sv = __sinf(fmaf(ac, z, p[c]));
  out[((size_t)n * L + l) * 256 + c] = z + sv * sv / ac;
}

// ---------------------------------------------------------------------------
extern "C" void kernel_launch(void* const* d_in, const int* in_sizes, int n_in,
                              void* d_out, int out_size, void* d_ws, size_t ws_size,
                              hipStream_t stream) {
  const float* x  = (const float*)d_in[0];
  const float* w1 = (const float*)d_in[1];
  const float* g1 = (const float*)d_in[2];
  const float* b1 = (const float*)d_in[3];
  const float* a1 = (const float*)d_in[4];
  const float* p1 = (const float*)d_in[5];
  const float* w2 = (const float*)d_in[6];
  const float* g2 = (const float*)d_in[7];
  const float* b2 = (const float*)d_in[8];
  const float* a2 = (const float*)d_in[9];
  const float* p2 = (const float*)d_in[10];
  const float* w3 = (const float*)d_in[11];
  const float* g3 = (const float*)d_in[12];
  const float* b3 = (const float*)d_in[13];
  const float* a3 = (const float*)d_in[14];
  const float* p3 = (const float*)d_in[15];
  const float* w4 = (const float*)d_in[16];
  const float* g4 = (const float*)d_in[17];
  const float* b4 = (const float*)d_in[18];
  const float* a4 = (const float*)d_in[19];
  const float* p4 = (const float*)d_in[20];
  float* out = (float*)d_out;
  char* ws = (char*)d_ws;

  const int N  = 32;
  const int L0 = 320000;
  const int L1 = 64001, P1 = 64004;
  const int L2 = 16001, P2 = 16004;
  const int L3 = 4001,  P3 = 4004;
  const int L4 = 1001,  P4 = 1004;
  // bf16 activation pitches: must cover 4*(ceil(Lout/64)*64 - 1) + 8, % 8 == 0
  const int PB1 = 64264;   // >= 4*16063 + 8
  const int PB2 = 16136;   // >= 4*4031  + 8
  const int PB3 = 4104;    // >= 4*1023  + 8

  const double ic1 = 1.0 / (32.0 * 1.0 * 10.0);

  // fixed ws region
  double* acc = (double*)ws;                                   // 260 doubles
  unsigned short* q2 = (unsigned short*)(ws + 4096);           // 16384 bf16
  unsigned short* q3 = (unsigned short*)(ws + 65536);          // 65536 bf16
  unsigned short* q4 = (unsigned short*)(ws + 262144);         // 262144 bf16
  const size_t fixedEnd = 1048576;

  const size_t aPer  = (size_t)32 * P1;    // floats; y1 bf16 fits in half; y3 fp32 fits
  const size_t bPer  = (size_t)64 * P2;    // floats; y2 (>= y4 = 256*P4)
  const size_t xbPer = (size_t)32 * PB1;   // bf16 elems; xb1 (>= xb2, xb3)
  const size_t perSampleBytes = (aPer + bPer) * 4 + xbPer * 2;  // ~16.4 MB

  int NC = (ws_size > fixedEnd) ? (int)((ws_size - fixedEnd) / perSampleBytes) : 0;
  if (NC < 1) NC = 1;
  if (NC > N) NC = N;

  float* bufA = (float*)(ws + fixedEnd);
  float* bufB = bufA + aPer * NC;
  unsigned short* XB = (unsigned short*)(bufB + bPer * NC);
  unsigned short* bufAh = (unsigned short*)bufA;   // y1 as bf16

  hipLaunchKernelGGL(zero_acc_kernel, dim3(1), dim3(512), 0, stream, acc);
  hipLaunchKernelGGL(wabs_kernel, dim3(64, 4), dim3(256), 0, stream,
                     w1, w2, w3, w4, acc + 256);
  hipLaunchKernelGGL(wprep_kernel, dim3(64, 3), dim3(256), 0, stream,
                     w2, w3, w4, acc + 256, q2, q3, q4);

  for (int nb = 0; nb < N; nb += NC) {
    int nc = (N - nb < NC) ? (N - nb) : NC;
    const float* xc = x + (size_t)nb * L0;

    // block 1: LDS-staged fp32 conv -> bf16 y1
    hipLaunchKernelGGL(conv1_kernel, dim3((L1 + 255) / 256, 4, nc), dim3(256), 0, stream,
                       xc, w1, acc + 256, ic1, bufAh, acc + 0 + 2 * nb, L0, L1, P1);
    hipLaunchKernelGGL((norm_bf16_kernel<unsigned short>),
                       dim3((PB1 + 1023) / 1024, 32, nc), dim3(256), 0, stream,
                       bufAh, acc + 0 + 2 * nb, g1, b1, a1, p1, XB, L1, P1, PB1,
                       1.0 / (32.0 * (double)L1));
    // block 2 (MFMA)
    hipLaunchKernelGGL((conv_mfma_kernel<32, 64>), dim3((L2 + 63) / 64, 1, nc), dim3(256), 0, stream,
                       XB, q2, bufB, acc + 64 + 2 * nb, PB1, L2, P2);
    hipLaunchKernelGGL((norm_bf16_kernel<float>),
                       dim3((PB2 + 1023) / 1024, 64, nc), dim3(256), 0, stream,
                       bufB, acc + 64 + 2 * nb, g2, b2, a2, p2, XB, L2, P2, PB2,
                       1.0 / (64.0 * (double)L2));
    // block 3 (MFMA)
    hipLaunchKernelGGL((conv_mfma_kernel<64, 128>), dim3((L3 + 63) / 64, 2, nc), dim3(256), 0, stream,
                       XB, q3, bufA, acc + 128 + 2 * nb, PB2, L3, P3);
    hipLaunchKernelGGL((norm_bf16_kernel<float>),
                       dim3((PB3 + 1023) / 1024, 128, nc), dim3(256), 0, stream,
                       bufA, acc + 128 + 2 * nb, g3, b3, a3, p3, XB, L3, P3, PB3,
                       1.0 / (128.0 * (double)L3));
    // block 4 (MFMA) + fused transpose epilogue
    hipLaunchKernelGGL((conv_mfma_kernel<128, 256>), dim3((L4 + 63) / 64, 4, nc), dim3(256), 0, stream,
                       XB, q4, bufB, acc + 192 + 2 * nb, PB3, L4, P4);
    hipLaunchKernelGGL(norm4t_kernel, dim3(L4, 1, nc), dim3(256), 0, stream,
                       bufB, acc + 192 + 2 * nb, g4, b4, a4, p4,
                       out + (size_t)nb * L4 * 256, L4, P4,
                       1.0 / (256.0 * (double)L4));
  }
}

// Round 13
// 577.234 us; speedup vs baseline: 3.6983x; 2.0202x over previous
//
#include <hip/hip_runtime.h>
#include <hip/hip_bf16.h>
#include <math.h>

#define EPS_GN 1e-5f
#define ACC_DOUBLES 260

typedef __attribute__((ext_vector_type(8))) short bf16x8;   // 8 bf16 (4 VGPR)
typedef __attribute__((ext_vector_type(4))) float f32x4;    // MFMA acc

// ---------------------------------------------------------------------------
// block-wide (sum,sumsq) reduce; thread 0 STORES to dst[0..1] (no atomics).
// ---------------------------------------------------------------------------
__device__ __forceinline__ void block_reduce_store(double s, double s2, double* dst) {
  #pragma unroll
  for (int o = 32; o > 0; o >>= 1) {
    s  += __shfl_down(s, o, 64);
    s2 += __shfl_down(s2, o, 64);
  }
  __shared__ double red[8];
  int wv = threadIdx.x >> 6;
  if ((threadIdx.x & 63) == 0) { red[wv] = s; red[4 + wv] = s2; }
  __syncthreads();
  if (threadIdx.x == 0) {
    dst[0] = red[0] + red[1] + red[2] + red[3];
    dst[1] = red[4] + red[5] + red[6] + red[7];
  }
}

__device__ __forceinline__ float quant_scale(const double* wsum, double invCnt) {
  return (float)(wsum[0] * invCnt) + 1e-8f;
}

__device__ __forceinline__ float quant_w(float w, float scale) {
  float r = rintf(w / scale);               // round-half-even == jnp.round
  r = fminf(1.f, fmaxf(-1.f, r));
  return r * scale;
}

__device__ __forceinline__ unsigned short f2bf(float v) {
  union { __hip_bfloat16 h; unsigned short u; } cv;
  cv.h = __float2bfloat16(v);
  return cv.u;
}

__device__ __forceinline__ float bf2f(unsigned short u) {
  union { unsigned int i; float f; } cv;
  cv.i = ((unsigned int)u) << 16;
  return cv.f;
}

__device__ __forceinline__ float loadS(const float* p) { return *p; }
__device__ __forceinline__ float loadS(const unsigned short* p) { return bf2f(*p); }
__device__ __forceinline__ void load4v(const float* p, float* v) {
  float4 t = *reinterpret_cast<const float4*>(p);
  v[0] = t.x; v[1] = t.y; v[2] = t.z; v[3] = t.w;
}
__device__ __forceinline__ void load4v(const unsigned short* p, float* v) {
  union { unsigned short s[4]; uint2 u; } t;
  t.u = *reinterpret_cast<const uint2*>(p);
  v[0] = bf2f(t.s[0]); v[1] = bf2f(t.s[1]); v[2] = bf2f(t.s[2]); v[3] = bf2f(t.s[3]);
}

// ---------------------------------------------------------------------------
__global__ void zero_acc_kernel(double* acc) {  // <<<1,512>>>
  if (threadIdx.x < ACC_DOUBLES) acc[threadIdx.x] = 0.0;
}

// ---------------------------------------------------------------------------
// Parallel sum(|w|), grid = (64, 4), block = 256, atomicAdd per layer
// (only 64 blocks/layer -> negligible contention).
// ---------------------------------------------------------------------------
__global__ __launch_bounds__(256) void wabs_kernel(
    const float* __restrict__ w1, const float* __restrict__ w2,
    const float* __restrict__ w3, const float* __restrict__ w4,
    double* __restrict__ wsum) {
  int layer = blockIdx.y;
  const float* w; int cnt;
  if      (layer == 0) { w = w1; cnt = 32  * 1   * 10; }
  else if (layer == 1) { w = w2; cnt = 64  * 32  * 8;  }
  else if (layer == 2) { w = w3; cnt = 128 * 64  * 8;  }
  else                 { w = w4; cnt = 256 * 128 * 8;  }

  double s = 0.0;
  for (int i = blockIdx.x * 256 + threadIdx.x; i < cnt; i += gridDim.x * 256)
    s += (double)fabsf(w[i]);
  #pragma unroll
  for (int o = 32; o > 0; o >>= 1) s += __shfl_down(s, o, 64);
  __shared__ double red[4];
  if ((threadIdx.x & 63) == 0) red[threadIdx.x >> 6] = s;
  __syncthreads();
  if (threadIdx.x == 0)
    atomicAdd(&wsum[layer], red[0] + red[1] + red[2] + red[3]);
}

// ---------------------------------------------------------------------------
// Quantize + convert weights of layers 2-4 to bf16. grid = (64, 3).
// ---------------------------------------------------------------------------
__global__ __launch_bounds__(256) void wprep_kernel(
    const float* __restrict__ w2, const float* __restrict__ w3,
    const float* __restrict__ w4, const double* __restrict__ wsum,
    unsigned short* __restrict__ q2, unsigned short* __restrict__ q3,
    unsigned short* __restrict__ q4) {
  int ly = blockIdx.y;
  const float* w; unsigned short* q; int cnt;
  if      (ly == 0) { w = w2; q = q2; cnt = 64  * 32  * 8; }
  else if (ly == 1) { w = w3; q = q3; cnt = 128 * 64  * 8; }
  else              { w = w4; q = q4; cnt = 256 * 128 * 8; }
  float scale = quant_scale(wsum + ly + 1, 1.0 / (double)cnt);
  for (int i = blockIdx.x * 256 + threadIdx.x; i < cnt; i += gridDim.x * 256)
    q[i] = f2bf(quant_w(w[i], scale));
}

// ---------------------------------------------------------------------------
// Per-sample partial-stat reduce: block zn sums cnt double2 partials and
// STORES acc[2*zn .. 2*zn+1] (accL pre-offset by layer + chunk). grid=(nc).
// ---------------------------------------------------------------------------
__global__ __launch_bounds__(256) void stat_reduce_kernel(
    const double* __restrict__ part, int cnt, double* __restrict__ accL) {
  int zn = blockIdx.x;
  const double* p = part + (size_t)zn * 512;
  double s = 0.0, s2 = 0.0;
  for (int i = threadIdx.x; i < cnt; i += 256) { s += p[2 * i]; s2 += p[2 * i + 1]; }
  block_reduce_store(s, s2, accL + 2 * zn);   // single writer per sample
}

// ---------------------------------------------------------------------------
// Block 1 conv: cin=1, cout=32 (ALL in one block), k=10, s=5, pad=5.
// LDS-staged input, bf16 output, per-block stat partials (no atomics).
// grid: (ceil(L1/256), 1, nc)
// ---------------------------------------------------------------------------
__global__ __launch_bounds__(256) void conv1_kernel(
    const float* __restrict__ x, const float* __restrict__ w,
    const double* __restrict__ wsum, double invCnt,
    unsigned short* __restrict__ out, double* __restrict__ part,
    int Lin, int Lout, int Pout) {
  const int CPT = 32, K = 10, S = 5;
  __shared__ __align__(16) float xin[1300];   // 256*5+10 = 1290
  __shared__ float wlds[CPT * K];             // 320

  int n   = blockIdx.z;
  int l0  = blockIdx.x * 256;
  int l   = l0 + threadIdx.x;

  {
    float scale = quant_scale(wsum, invCnt);
    for (int i = threadIdx.x; i < CPT * K; i += 256)
      wlds[i] = quant_w(w[i], scale);
  }

  const float* ip = x + (size_t)n * Lin;
  int wstart = l0 * S - 5;
  int astart = wstart & ~3;
  int off    = wstart - astart;    // 0..3
  for (int i = threadIdx.x; i < 324; i += 256) {
    int gi = astart + i * 4;
    float4 v;
    if (gi >= 0 && gi + 4 <= Lin) {
      v = *reinterpret_cast<const float4*>(ip + gi);
    } else {
      v.x = (gi + 0 >= 0 && gi + 0 < Lin) ? ip[gi + 0] : 0.f;
      v.y = (gi + 1 >= 0 && gi + 1 < Lin) ? ip[gi + 1] : 0.f;
      v.z = (gi + 2 >= 0 && gi + 2 < Lin) ? ip[gi + 2] : 0.f;
      v.w = (gi + 3 >= 0 && gi + 3 < Lin) ? ip[gi + 3] : 0.f;
    }
    *reinterpret_cast<float4*>(xin + i * 4) = v;
  }
  __syncthreads();

  double s = 0.0, s2 = 0.0;
  if (l < Lout) {
    float win[K];
    int base = threadIdx.x * S + off;
    #pragma unroll
    for (int t = 0; t < K; ++t) win[t] = xin[base + t];
    #pragma unroll
    for (int j = 0; j < CPT; ++j) {
      float acv = 0.f;
      #pragma unroll
      for (int t = 0; t < K; ++t)
        acv = fmaf(win[t], wlds[j * K + t], acv);
      out[((size_t)n * 32 + j) * Pout + l] = f2bf(acv);
      double v = acv; s += v; s2 += v * v;
    }
  }
  block_reduce_store(s, s2, part + ((size_t)n * 512 + (size_t)blockIdx.x * 2));
}

// ---------------------------------------------------------------------------
// LayerNorm + snake -> bf16 copy with +4 left shift and zero padding to PB.
// grid: (ceil(PB/1024), C, nc)
// ---------------------------------------------------------------------------
template <typename T>
__global__ __launch_bounds__(256) void norm_bf16_kernel(
    const T* __restrict__ y, const double* __restrict__ acc_b,
    const float* __restrict__ g, const float* __restrict__ b,
    const float* __restrict__ a, const float* __restrict__ p,
    unsigned short* __restrict__ xb,
    int L, int P, int PB, double invCount) {
  int n = blockIdx.z;
  int c = blockIdx.y;
  int i0 = (blockIdx.x * 256 + threadIdx.x) * 4;
  if (i0 >= PB) return;
  double sd  = acc_b[2 * n];
  double s2d = acc_b[2 * n + 1];
  double mu_d = sd * invCount;
  float mu  = (float)mu_d;
  float var = (float)(s2d * invCount - mu_d * mu_d);
  float rs  = rsqrtf(var + EPS_GN);
  float gc = g[c], bc = b[c], ac = a[c], pc = p[c];
  float grs = rs * gc;
  const T* yr = y + ((size_t)n * gridDim.y + c) * P;
  unsigned short* xr = xb + ((size_t)n * gridDim.y + c) * PB;

  int lstart = i0 - 4;
  float vin[4];
  bool val[4];
  if (lstart >= 0 && lstart + 4 <= L) {
    load4v(yr + lstart, vin);
    val[0] = val[1] = val[2] = val[3] = true;
  } else {
    #pragma unroll
    for (int r = 0; r < 4; ++r) {
      int lr = lstart + r;
      val[r] = (lr >= 0 && lr < L);
      vin[r] = val[r] ? loadS(yr + lr) : 0.f;
    }
  }

  unsigned short ov[4];
  #pragma unroll
  for (int r = 0; r < 4; ++r) {
    float v = 0.f;
    if (val[r]) {
      float z = (vin[r] - mu) * grs + bc;
      float sv = __sinf(fmaf(ac, z, pc));
      v = z + sv * sv / ac;
    }
    ov[r] = f2bf(v);
  }
  if (i0 + 4 <= PB) {
    union { unsigned short s[4]; uint2 u; } pk;
    pk.s[0] = ov[0]; pk.s[1] = ov[1]; pk.s[2] = ov[2]; pk.s[3] = ov[3];
    *reinterpret_cast<uint2*>(xr + i0) = pk.u;
  } else {
    for (int r = 0; r < 4 && i0 + r < PB; ++r) xr[i0 + r] = ov[r];
  }
}

// ---------------------------------------------------------------------------
// Convs 2-4 as bf16 MFMA implicit GEMM; per-block stat partials (no atomics).
// grid: (ceil(Lout/64), COUT/64, nc)
// ---------------------------------------------------------------------------
template <int CIN, int COUT>
__global__ __launch_bounds__(256) void conv_mfma_kernel(
    const unsigned short* __restrict__ xb, const unsigned short* __restrict__ wq,
    float* __restrict__ out, double* __restrict__ part,
    int PBin, int Lout, int Pout) {
  const int KT = CIN * 8;
  int n    = blockIdx.z;
  int lane = threadIdx.x & 63;
  int wv   = threadIdx.x >> 6;
  int grp  = lane >> 4;        // 0..3
  int lr   = lane & 15;        // 0..15
  int co16 = blockIdx.y * 64 + wv * 16;
  int lb   = blockIdx.x * 64;

  f32x4 a0 = {0.f, 0.f, 0.f, 0.f};
  f32x4 a1 = {0.f, 0.f, 0.f, 0.f};
  f32x4 a2 = {0.f, 0.f, 0.f, 0.f};
  f32x4 a3 = {0.f, 0.f, 0.f, 0.f};

  const unsigned short* arow = wq + (size_t)(co16 + lr) * KT + grp * 8;
  const unsigned short* xbn  = xb + ((size_t)n * CIN + grp) * PBin;
  int c0 = (lb + lr) * 4;

  #pragma unroll 4
  for (int kk = 0; kk < KT / 32; ++kk) {
    bf16x8 af = *reinterpret_cast<const bf16x8*>(arow + kk * 32);
    const unsigned short* xr = xbn + (size_t)(kk * 4) * PBin;
    union { uint2 u[2]; bf16x8 v; } b0, b1, b2, b3;
    b0.u[0] = *(const uint2*)(xr + c0);       b0.u[1] = *(const uint2*)(xr + c0 + 4);
    b1.u[0] = *(const uint2*)(xr + c0 + 64);  b1.u[1] = *(const uint2*)(xr + c0 + 68);
    b2.u[0] = *(const uint2*)(xr + c0 + 128); b2.u[1] = *(const uint2*)(xr + c0 + 132);
    b3.u[0] = *(const uint2*)(xr + c0 + 192); b3.u[1] = *(const uint2*)(xr + c0 + 196);
    a0 = __builtin_amdgcn_mfma_f32_16x16x32_bf16(af, b0.v, a0, 0, 0, 0);
    a1 = __builtin_amdgcn_mfma_f32_16x16x32_bf16(af, b1.v, a1, 0, 0, 0);
    a2 = __builtin_amdgcn_mfma_f32_16x16x32_bf16(af, b2.v, a2, 0, 0, 0);
    a3 = __builtin_amdgcn_mfma_f32_16x16x32_bf16(af, b3.v, a3, 0, 0, 0);
  }

  double s = 0.0, s2 = 0.0;
  float* ob = out + (size_t)n * COUT * Pout;
  {
    int l = lb + 0 * 16 + lr;
    if (l < Lout) {
      #pragma unroll
      for (int r = 0; r < 4; ++r) {
        float v = a0[r];
        ob[(size_t)(co16 + grp * 4 + r) * Pout + l] = v;
        s += v; s2 += (double)v * v;
      }
    }
  }
  {
    int l = lb + 1 * 16 + lr;
    if (l < Lout) {
      #pragma unroll
      for (int r = 0; r < 4; ++r) {
        float v = a1[r];
        ob[(size_t)(co16 + grp * 4 + r) * Pout + l] = v;
        s += v; s2 += (double)v * v;
      }
    }
  }
  {
    int l = lb + 2 * 16 + lr;
    if (l < Lout) {
      #pragma unroll
      for (int r = 0; r < 4; ++r) {
        float v = a2[r];
        ob[(size_t)(co16 + grp * 4 + r) * Pout + l] = v;
        s += v; s2 += (double)v * v;
      }
    }
  }
  {
    int l = lb + 3 * 16 + lr;
    if (l < Lout) {
      #pragma unroll
      for (int r = 0; r < 4; ++r) {
        float v = a3[r];
        ob[(size_t)(co16 + grp * 4 + r) * Pout + l] = v;
        s += v; s2 += (double)v * v;
      }
    }
  }
  int bflat = blockIdx.y * gridDim.x + blockIdx.x;
  block_reduce_store(s, s2, part + ((size_t)n * 512 + (size_t)bflat * 2));
}

// ---------------------------------------------------------------------------
// Final block: norm + snake + NCH->NHC transpose into d_out (pre-offset).
// grid: (L, 1, nc), block: 256 (=C)
// ---------------------------------------------------------------------------
__global__ __launch_bounds__(256) void norm4t_kernel(
    const float* __restrict__ y, const double* __restrict__ acc_b,
    const float* __restrict__ g, const float* __restrict__ b,
    const float* __restrict__ a, const float* __restrict__ p,
    float* __restrict__ out, int L, int P, double invCount) {
  int n = blockIdx.z;
  int l = blockIdx.x;
  int c = threadIdx.x;
  double sd  = acc_b[2 * n];
  double s2d = acc_b[2 * n + 1];
  double mu_d = sd * invCount;
  float mu  = (float)mu_d;
  float var = (float)(s2d * invCount - mu_d * mu_d);
  float rs  = rsqrtf(var + EPS_GN);
  float v  = y[((size_t)n * 256 + c) * P + l];
  float z  = (v - mu) * rs * g[c] + b[c];
  float ac = a[c];
  float sv = __sinf(fmaf(ac, z, p[c]));
  out[((size_t)n * L + l) * 256 + c] = z + sv * sv / ac;
}

// ---------------------------------------------------------------------------
extern "C" void kernel_launch(void* const* d_in, const int* in_sizes, int n_in,
                              void* d_out, int out_size, void* d_ws, size_t ws_size,
                              hipStream_t stream) {
  const float* x  = (const float*)d_in[0];
  const float* w1 = (const float*)d_in[1];
  const float* g1 = (const float*)d_in[2];
  const float* b1 = (const float*)d_in[3];
  const float* a1 = (const float*)d_in[4];
  const float* p1 = (const float*)d_in[5];
  const float* w2 = (const float*)d_in[6];
  const float* g2 = (const float*)d_in[7];
  const float* b2 = (const float*)d_in[8];
  const float* a2 = (const float*)d_in[9];
  const float* p2 = (const float*)d_in[10];
  const float* w3 = (const float*)d_in[11];
  const float* g3 = (const float*)d_in[12];
  const float* b3 = (const float*)d_in[13];
  const float* a3 = (const float*)d_in[14];
  const float* p3 = (const float*)d_in[15];
  const float* w4 = (const float*)d_in[16];
  const float* g4 = (const float*)d_in[17];
  const float* b4 = (const float*)d_in[18];
  const float* a4 = (const float*)d_in[19];
  const float* p4 = (const float*)d_in[20];
  float* out = (float*)d_out;
  char* ws = (char*)d_ws;

  const int N  = 32;
  const int L0 = 320000;
  const int L1 = 64001, P1 = 64004;
  const int L2 = 16001, P2 = 16004;
  const int L3 = 4001,  P3 = 4004;
  const int L4 = 1001,  P4 = 1004;
  const int PB1 = 64264;   // bf16 pitches (cover 4*(ceil(L/64)*64-1)+8, %8==0)
  const int PB2 = 16136;
  const int PB3 = 4104;

  const double ic1 = 1.0 / (32.0 * 1.0 * 10.0);

  // fixed ws region
  double* acc = (double*)ws;                                   // 260 doubles
  unsigned short* q2 = (unsigned short*)(ws + 4096);           // 16384 bf16
  unsigned short* q3 = (unsigned short*)(ws + 65536);          // 65536 bf16
  unsigned short* q4 = (unsigned short*)(ws + 262144);         // 262144 bf16
  double* parts = (double*)(ws + 786432);  // 4 layers x 32 samples x 512 dbl
  double* partL1 = parts;
  double* partL2 = parts + (size_t)32 * 512;
  double* partL3 = parts + (size_t)64 * 512;
  double* partL4 = parts + (size_t)96 * 512;
  const size_t fixedEnd = 786432 + (size_t)4 * 32 * 512 * 8;   // 1,835,008 B

  const size_t aPer  = (size_t)32 * P1;    // floats; y1(bf16) & y3(fp32) fit
  const size_t bPer  = (size_t)64 * P2;    // floats; y2 (>= y4)
  const size_t xbPer = (size_t)32 * PB1;   // bf16; xb1 (>= xb2, xb3)
  const size_t perSampleBytes = (aPer + bPer) * 4 + xbPer * 2;

  int NC = (ws_size > fixedEnd) ? (int)((ws_size - fixedEnd) / perSampleBytes) : 0;
  if (NC < 1) NC = 1;
  if (NC > N) NC = N;

  float* bufA = (float*)(ws + fixedEnd);
  float* bufB = bufA + aPer * NC;
  unsigned short* XB = (unsigned short*)(bufB + bPer * NC);
  unsigned short* bufAh = (unsigned short*)bufA;

  hipLaunchKernelGGL(zero_acc_kernel, dim3(1), dim3(512), 0, stream, acc);
  hipLaunchKernelGGL(wabs_kernel, dim3(64, 4), dim3(256), 0, stream,
                     w1, w2, w3, w4, acc + 256);
  hipLaunchKernelGGL(wprep_kernel, dim3(64, 3), dim3(256), 0, stream,
                     w2, w3, w4, acc + 256, q2, q3, q4);

  const int NB1 = (L1 + 255) / 256;          // 251
  const int NB2 = (L2 + 63) / 64;            // 251 (x 1 y)
  const int NB3 = ((L3 + 63) / 64) * 2;      // 63 x 2 = 126
  const int NB4 = ((L4 + 63) / 64) * 4;      // 16 x 4 = 64

  for (int nb = 0; nb < N; nb += NC) {
    int nc = (N - nb < NC) ? (N - nb) : NC;
    const float* xc = x + (size_t)nb * L0;

    // block 1
    hipLaunchKernelGGL(conv1_kernel, dim3(NB1, 1, nc), dim3(256), 0, stream,
                       xc, w1, acc + 256, ic1, bufAh, partL1, L0, L1, P1);
    hipLaunchKernelGGL(stat_reduce_kernel, dim3(nc), dim3(256), 0, stream,
                       partL1, NB1, acc + 0 + 2 * nb);
    hipLaunchKernelGGL((norm_bf16_kernel<unsigned short>),
                       dim3((PB1 + 1023) / 1024, 32, nc), dim3(256), 0, stream,
                       bufAh, acc + 0 + 2 * nb, g1, b1, a1, p1, XB, L1, P1, PB1,
                       1.0 / (32.0 * (double)L1));
    // block 2
    hipLaunchKernelGGL((conv_mfma_kernel<32, 64>), dim3((L2 + 63) / 64, 1, nc), dim3(256), 0, stream,
                       XB, q2, bufB, partL2, PB1, L2, P2);
    hipLaunchKernelGGL(stat_reduce_kernel, dim3(nc), dim3(256), 0, stream,
                       partL2, NB2, acc + 64 + 2 * nb);
    hipLaunchKernelGGL((norm_bf16_kernel<float>),
                       dim3((PB2 + 1023) / 1024, 64, nc), dim3(256), 0, stream,
                       bufB, acc + 64 + 2 * nb, g2, b2, a2, p2, XB, L2, P2, PB2,
                       1.0 / (64.0 * (double)L2));
    // block 3
    hipLaunchKernelGGL((conv_mfma_kernel<64, 128>), dim3((L3 + 63) / 64, 2, nc), dim3(256), 0, stream,
                       XB, q3, bufA, partL3, PB2, L3, P3);
    hipLaunchKernelGGL(stat_reduce_kernel, dim3(nc), dim3(256), 0, stream,
                       partL3, NB3, acc + 128 + 2 * nb);
    hipLaunchKernelGGL((norm_bf16_kernel<float>),
                       dim3((PB3 + 1023) / 1024, 128, nc), dim3(256), 0, stream,
                       bufA, acc + 128 + 2 * nb, g3, b3, a3, p3, XB, L3, P3, PB3,
                       1.0 / (128.0 * (double)L3));
    // block 4 + fused transpose epilogue
    hipLaunchKernelGGL((conv_mfma_kernel<128, 256>), dim3((L4 + 63) / 64, 4, nc), dim3(256), 0, stream,
                       XB, q4, bufB, partL4, PB3, L4, P4);
    hipLaunchKernelGGL(stat_reduce_kernel, dim3(nc), dim3(256), 0, stream,
                       partL4, NB4, acc + 192 + 2 * nb);
    hipLaunchKernelGGL(norm4t_kernel, dim3(L4, 1, nc), dim3(256), 0, stream,
                       bufB, acc + 192 + 2 * nb, g4, b4, a4, p4,
                       out + (size_t)nb * L4 * 256, L4, P4,
                       1.0 / (256.0 * (double)L4));
  }
}